// Round 1
// 143.144 us; speedup vs baseline: 1.2485x; 1.2485x over previous
//
#include <hip/hip_runtime.h>
#include <stdint.h>

// Problem constants (match reference)
#define N_PRIORS 2097152
#define KTOP 512
#define NBINS 2048
#define K1BLK 2048
#define SCAP 32                  // stash slots per k1 block (mean 0.39, Poisson-safe)
#define SELCAP 2048
#define SSTASH 0.9915f           // stash pre-filter; expected ~800 >= 512 (10 sigma)

// ws layout:
// [0, 8K)        u32 blk_cnt[2048]
// [8K, 8K+512K)  u64 stash[2048*32]
// Overlaid on the stash region (stash is dead after k2a's gather phase;
// in-kernel barriers order gather-reads before decode-writes):
//   +8192   float4 bpk_g[512]     (8 KB)   pixel boxes
//   +16384  float  sar_g[512]     (2 KB)   areas
//   +18432  float  ssc_g[512]     (2 KB)   scores
//   +20480  u64    keepw0_g[8]    (64 B)   valid bits (pre-NMS)
//   +20544  u32    rowany_g[16]   (64 B)   row-suppresses-anything bits
//   +20608  u64    supW_g[512*8]  (32 KB)  suppression matrix

__device__ __forceinline__ uint64_t pack_key(float s, int idx) {
    // descending score, ascending index tie-break (== stable top_k)
    return ((uint64_t)__float_as_uint(s) << 32) | (uint32_t)(~idx);
}

__device__ __forceinline__ float score_of(float c0, float c1) {
    #pragma clang fp contract(off)
    float m  = fmaxf(c0, c1);
    float e0 = expf(c0 - m);
    float e1 = expf(c1 - m);
    return e1 / (e0 + e1);
}

__device__ __forceinline__ int bin_of(float s) {
    #pragma clang fp contract(off)
    int b = (int)((s - 0.9f) * 20480.0f);   // 2048 bins over (0.9, 1.0]
    return b > (NBINS - 1) ? (NBINS - 1) : b;
}

// K1: stream conf once (full grid); stash s > SSTASH into per-block regions.
// Zero global atomics; LDS counter only.  (UNCHANGED from baseline.)
__global__ void k1_stash(const float4* __restrict__ conf4,
                         uint32_t* __restrict__ blk_cnt,
                         uint64_t* __restrict__ stash) {
    #pragma clang fp contract(off)
    __shared__ uint32_t lcnt;
    int t = threadIdx.x;            // 256 threads
    int blk = blockIdx.x;           // 2048 blocks, 512 float4 (1024 elems) each
    if (t == 0) lcnt = 0;
    __syncthreads();
    uint64_t* reg = stash + (size_t)blk * SCAP;
    #pragma unroll
    for (int i = 0; i < 2; ++i) {
        int f4i = blk * 512 + t + 256 * i;
        float4 c = conf4[f4i];
        float s0 = score_of(c.x, c.y);
        float s1 = score_of(c.z, c.w);
        if (s0 > SSTASH) {
            uint32_t p = atomicAdd(&lcnt, 1u);
            if (p < SCAP) reg[p] = pack_key(s0, f4i * 2);
        }
        if (s1 > SSTASH) {
            uint32_t p = atomicAdd(&lcnt, 1u);
            if (p < SCAP) reg[p] = pack_key(s1, f4i * 2 + 1);
        }
    }
    __syncthreads();
    if (t == 0) blk_cnt[blk] = (lcnt <= SCAP) ? lcnt : 0xFFFFFFFFu;
}

// K2a: single block: gather stash -> (exact fallback if needed) -> bitonic
// sort -> decode top-512 -> write boxes/areas/scores/valid-bits to ws.
// NOTE: bpk_g/sar_g/ssc_g overlay the stash region -- no __restrict__ on
// stash/outputs so the compiler cannot assume no-alias (barriers order them).
__launch_bounds__(1024)
__global__ void k2a_sort(const float4* __restrict__ loc,
                         const float4* __restrict__ priors,
                         const float4* __restrict__ conf4,
                         const uint32_t* __restrict__ blk_cnt,
                         const uint64_t* stash,
                         float4* bpk_g,
                         float* sar_g,
                         float* ssc_g,
                         uint64_t* keepw0_g) {
    #pragma clang fp contract(off)
    __shared__ uint64_t sel[SELCAP];        // 16 KB
    __shared__ uint32_t hist[NBINS];        // 8 KB (fallback only)
    __shared__ uint32_t nselS, fbS;
    __shared__ int bmaxS;

    int tid = threadIdx.x;          // 1024 threads
    int lane = tid & 63, wv = tid >> 6;

    if (tid == 0) { nselS = 0u; fbS = 0u; bmaxS = 0; }
    __syncthreads();

    // ---- gather stash entries (breadth-first, ~800 expected) ----
    for (int b = tid; b < K1BLK; b += 1024) {
        uint32_t c = blk_cnt[b];
        if (c == 0xFFFFFFFFu) { atomicOr(&fbS, 1u); c = 0; }
        const uint64_t* regp = stash + (size_t)b * SCAP;
        for (uint32_t j = 0; j < c; ++j) {
            uint64_t k = regp[j];
            uint32_t p = atomicAdd(&nselS, 1u);
            if (p < SELCAP) sel[p] = k; else atomicOr(&fbS, 1u);
        }
    }
    __syncthreads();
    uint32_t n = nselS;
    bool fb = (fbS != 0u) || (n < KTOP) || (n > SELCAP);
    __syncthreads();

    if (fb) {
        // ---- exact fallback: 2-pass histogram select over all of conf ----
        if (tid == 0) nselS = 0u;
        for (int b = tid; b < NBINS; b += 1024) hist[b] = 0u;
        __syncthreads();
        for (int f = tid; f < N_PRIORS / 2; f += 1024) {
            float4 c = conf4[f];
            float s0 = score_of(c.x, c.y);
            float s1 = score_of(c.z, c.w);
            if (s0 > 0.9f) atomicAdd(&hist[bin_of(s0)], 1u);
            if (s1 > 0.9f) atomicAdd(&hist[bin_of(s1)], 1u);
        }
        __syncthreads();
        for (int off = 1; off < NBINS; off <<= 1) {
            int b0 = tid, b1 = tid + 1024;
            uint32_t v0 = hist[b0] + ((b0 + off < NBINS) ? hist[b0 + off] : 0u);
            uint32_t v1 = hist[b1] + ((b1 + off < NBINS) ? hist[b1 + off] : 0u);
            __syncthreads();
            hist[b0] = v0; hist[b1] = v1;
            __syncthreads();
        }
        if (hist[tid] >= KTOP) atomicMax(&bmaxS, tid);
        if (hist[tid + 1024] >= KTOP) atomicMax(&bmaxS, tid + 1024);
        __syncthreads();
        int B = bmaxS;
        for (int f = tid; f < N_PRIORS / 2; f += 1024) {
            float4 c = conf4[f];
            float s0 = score_of(c.x, c.y);
            float s1 = score_of(c.z, c.w);
            if (s0 > 0.9f && bin_of(s0) >= B) {
                uint32_t p = atomicAdd(&nselS, 1u);
                if (p < SELCAP) sel[p] = pack_key(s0, 2 * f);
            }
            if (s1 > 0.9f && bin_of(s1) >= B) {
                uint32_t p = atomicAdd(&nselS, 1u);
                if (p < SELCAP) sel[p] = pack_key(s1, 2 * f + 1);
            }
        }
        __syncthreads();
        n = nselS; if (n > SELCAP) n = SELCAP;
        __syncthreads();
    }

    int P = KTOP; while (P < (int)n) P <<= 1;
    for (int t = tid; t < P; t += 1024) if (t >= (int)n) sel[t] = 0ull;
    __syncthreads();

    // ---- bitonic sort, descending (0-padding sinks) ----
    for (int k = 2; k <= P; k <<= 1) {
        for (int j = k >> 1; j > 0; j >>= 1) {
            for (int t = tid; t < P; t += 1024) {
                int ixj = t ^ j;
                if (ixj > t) {
                    uint64_t a = sel[t], b = sel[ixj];
                    bool sw = ((t & k) == 0) ? (a < b) : (a > b);
                    if (sw) { sel[t] = b; sel[ixj] = a; }
                }
            }
            __syncthreads();
        }
    }

    // ---- decode top-512 (exact numpy op order); valid bits via ballot ----
    {
        uint64_t key = (tid < KTOP) ? sel[tid] : 0ull;
        if (tid < KTOP) {
            float4 bb; float area, sc;
            if (key != 0ull) {
                sc = __uint_as_float((uint32_t)(key >> 32));
                int idx  = (int)(~(uint32_t)key);
                float4 l = loc[idx];
                float4 p = priors[idx];
                float cx = p.x + (l.x * 0.1f) * p.z;
                float cy = p.y + (l.y * 0.1f) * p.w;
                float w  = p.z * expf(l.z * 0.2f);
                float h  = p.w * expf(l.w * 0.2f);
                float x1 = cx - w * 0.5f;
                float y1 = cy - h * 0.5f;
                float x2 = x1 + w;
                float y2 = y1 + h;
                x1 *= 2048.0f; y1 *= 2048.0f; x2 *= 2048.0f; y2 *= 2048.0f;
                bb = make_float4(x1, y1, x2, y2);
                area = (x2 - x1 + 1.0f) * (y2 - y1 + 1.0f);
            } else {
                bb = make_float4(0.f, 0.f, 0.f, 0.f); area = 1.f; sc = 0.f;
            }
            bpk_g[tid] = bb; sar_g[tid] = area; ssc_g[tid] = sc;
        }
        uint64_t vb = __ballot(key != 0ull);    // wave w covers cols 64w..64w+63
        if (lane == 0 && wv < 8) keepw0_g[wv] = vb;
    }
}

// K2b: suppression matrix on 16 blocks (16 CUs). Block b owns rows
// [b*32, b*32+32); 4 waves x 8 rows. Lane L owns cols {64c+L}. Row bitmasks
// assembled by ballot: supW_g[r*8+c] bit L = (col 64c+L suppressed by row r).
// Identical FP ops as baseline -> bit-identical suppression decisions.
__launch_bounds__(256)
__global__ void k2b_supp(const float4* bpk_g, const float* sar_g,
                         uint64_t* supW_g, uint32_t* rowany_g) {
    #pragma clang fp contract(off)
    __shared__ float4 bpk[KTOP];            // 8 KB
    __shared__ float  sar[KTOP];            // 2 KB
    __shared__ uint32_t anyS;
    int tid = threadIdx.x;                  // 256 threads
    int lane = tid & 63, wv = tid >> 6;     // 4 waves
    if (tid == 0) anyS = 0u;
    for (int i = tid; i < KTOP; i += 256) { bpk[i] = bpk_g[i]; sar[i] = sar_g[i]; }
    __syncthreads();

    float4 cb0 = bpk[lane +   0], cb1 = bpk[lane +  64];
    float4 cb2 = bpk[lane + 128], cb3 = bpk[lane + 192];
    float4 cb4 = bpk[lane + 256], cb5 = bpk[lane + 320];
    float4 cb6 = bpk[lane + 384], cb7 = bpk[lane + 448];
    // identical formula+inputs as decode -> bit-identical areas
    float ca0 = (cb0.z - cb0.x + 1.0f) * (cb0.w - cb0.y + 1.0f);
    float ca1 = (cb1.z - cb1.x + 1.0f) * (cb1.w - cb1.y + 1.0f);
    float ca2 = (cb2.z - cb2.x + 1.0f) * (cb2.w - cb2.y + 1.0f);
    float ca3 = (cb3.z - cb3.x + 1.0f) * (cb3.w - cb3.y + 1.0f);
    float ca4 = (cb4.z - cb4.x + 1.0f) * (cb4.w - cb4.y + 1.0f);
    float ca5 = (cb5.z - cb5.x + 1.0f) * (cb5.w - cb5.y + 1.0f);
    float ca6 = (cb6.z - cb6.x + 1.0f) * (cb6.w - cb6.y + 1.0f);
    float ca7 = (cb7.z - cb7.x + 1.0f) * (cb7.w - cb7.y + 1.0f);

    #define SUPC(c, CB, CA) do { \
        float xx1 = fmaxf(rb.x, CB.x); float yy1 = fmaxf(rb.y, CB.y); \
        float xx2 = fminf(rb.z, CB.z); float yy2 = fminf(rb.w, CB.w); \
        float ww = fmaxf(xx2 - xx1 + 1.0f, 0.0f); \
        float hh = fmaxf(yy2 - yy1 + 1.0f, 0.0f); \
        float inter = ww * hh; \
        float iou = inter / (ra + (CA) - inter); \
        uint64_t wrd = __ballot(iou > 0.4f && (64 * (c) + lane) > r); \
        if (lane == 0) supW_g[r * 8 + (c)] = wrd; \
        any |= wrd; } while (0)

    uint32_t mybits = 0u;
    int rbase = blockIdx.x * 32 + wv * 8;
    for (int rr = 0; rr < 8; ++rr) {
        int r = rbase + rr;
        float4 rb = bpk[r];     // wave-uniform broadcast
        float ra = sar[r];
        uint64_t any = 0ull;
        SUPC(0, cb0, ca0); SUPC(1, cb1, ca1); SUPC(2, cb2, ca2); SUPC(3, cb3, ca3);
        SUPC(4, cb4, ca4); SUPC(5, cb5, ca5); SUPC(6, cb6, ca6); SUPC(7, cb7, ca7);
        if (lane == 0 && any != 0ull) mybits |= 1u << (r & 31);
    }
    #undef SUPC
    if (lane == 0 && mybits != 0u) atomicOr(&anyS, mybits);
    __syncthreads();
    if (tid == 0) rowany_g[blockIdx.x] = anyS;   // rows b*32.. -> word b exactly
}

// K2c: greedy bitmask scan (1 thread; rare rows) + epilogue.
__launch_bounds__(512)
__global__ void k2c_final(const float4* bpk_g, const float* ssc_g,
                          const uint64_t* keepw0_g, const uint32_t* rowany_g,
                          const uint64_t* supW_g, float* __restrict__ out) {
    #pragma clang fp contract(off)
    __shared__ uint64_t supW[KTOP * 8];     // 32 KB
    __shared__ uint64_t keepw[8];
    int tid = threadIdx.x;                  // 512 threads
    for (int i = tid; i < KTOP * 8; i += 512) supW[i] = supW_g[i];
    __syncthreads();

    if (tid == 0) {
        #define RA64(c) (((uint64_t)rowany_g[2*(c)]) | (((uint64_t)rowany_g[2*(c)+1]) << 32))
        uint64_t kp0 = keepw0_g[0], kp1 = keepw0_g[1], kp2 = keepw0_g[2], kp3 = keepw0_g[3];
        uint64_t kp4 = keepw0_g[4], kp5 = keepw0_g[5], kp6 = keepw0_g[6], kp7 = keepw0_g[7];
        #define APPLYROW(i) do { const uint64_t* rp = supW + (size_t)(i) * 8; \
            kp0 &= ~rp[0]; kp1 &= ~rp[1]; kp2 &= ~rp[2]; kp3 &= ~rp[3]; \
            kp4 &= ~rp[4]; kp5 &= ~rp[5]; kp6 &= ~rp[6]; kp7 &= ~rp[7]; } while (0)
        #define CHUNK(c, KPC) do { uint64_t ra = RA64(c); uint64_t m = (KPC) & ra; \
            while (m) { int b = __builtin_ctzll(m); APPLYROW((c) * 64 + b); \
                uint64_t above = (b == 63) ? 0ull : (~0ull << (b + 1)); \
                m = (KPC) & ra & above; } } while (0)
        CHUNK(0, kp0); CHUNK(1, kp1); CHUNK(2, kp2); CHUNK(3, kp3);
        CHUNK(4, kp4); CHUNK(5, kp5); CHUNK(6, kp6); CHUNK(7, kp7);
        keepw[0] = kp0; keepw[1] = kp1; keepw[2] = kp2; keepw[3] = kp3;
        keepw[4] = kp4; keepw[5] = kp5; keepw[6] = kp6; keepw[7] = kp7;
        #undef CHUNK
        #undef APPLYROW
        #undef RA64
    }
    __syncthreads();

    // ---- epilogue: [512,5], boxes /2048 (exact pow2), zeros if suppressed ----
    if (tid < KTOP) {
        const float inv = 1.0f / 2048.0f;
        int kb = (int)((keepw[tid >> 6] >> (tid & 63)) & 1ull);
        float4 bb = bpk_g[tid];
        float sc = ssc_g[tid];
        float* o = out + tid * 5;
        if (kb) {
            o[0] = bb.x * inv;
            o[1] = bb.y * inv;
            o[2] = bb.z * inv;
            o[3] = bb.w * inv;
            o[4] = sc;
        } else {
            o[0] = 0.f; o[1] = 0.f; o[2] = 0.f; o[3] = 0.f; o[4] = 0.f;
        }
    }
}

extern "C" void kernel_launch(void* const* d_in, const int* in_sizes, int n_in,
                              void* d_out, int out_size, void* d_ws, size_t ws_size,
                              hipStream_t stream) {
    const float* loc    = (const float*)d_in[0];   // [1,N,4]
    const float* conf   = (const float*)d_in[1];   // [1,N,2]
    const float* priors = (const float*)d_in[2];   // [N,4]
    float* out = (float*)d_out;                    // [512,5]

    uint8_t* ws = (uint8_t*)d_ws;
    uint32_t* blk_cnt = (uint32_t*)ws;             // 8 KB
    uint64_t* stash   = (uint64_t*)(ws + 8192);    // 512 KB
    // overlays on stash (dead after k2a gather):
    float4*   bpk_g    = (float4*)(ws + 8192);     // 8 KB
    float*    sar_g    = (float*)(ws + 16384);     // 2 KB
    float*    ssc_g    = (float*)(ws + 18432);     // 2 KB
    uint64_t* keepw0_g = (uint64_t*)(ws + 20480);  // 64 B
    uint32_t* rowany_g = (uint32_t*)(ws + 20544);  // 64 B
    uint64_t* supW_g   = (uint64_t*)(ws + 20608);  // 32 KB

    // no memset needed: blk_cnt fully written by K1; all overlay arrays are
    // fully written by their producer kernel before any consumer reads them.
    k1_stash<<<K1BLK, 256, 0, stream>>>((const float4*)conf, blk_cnt, stash);
    k2a_sort<<<1, 1024, 0, stream>>>((const float4*)loc, (const float4*)priors,
                                     (const float4*)conf, blk_cnt, stash,
                                     bpk_g, sar_g, ssc_g, keepw0_g);
    k2b_supp<<<16, 256, 0, stream>>>(bpk_g, sar_g, supW_g, rowany_g);
    k2c_final<<<1, 512, 0, stream>>>(bpk_g, ssc_g, keepw0_g, rowany_g, supW_g, out);
}

// Round 2
// 135.778 us; speedup vs baseline: 1.3162x; 1.0543x over previous
//
#include <hip/hip_runtime.h>
#include <stdint.h>

// Problem constants (match reference)
#define N_PRIORS 2097152
#define KTOP 512
#define NBINS 2048
#define K1BLK 2048
#define SCAP 32                  // stash slots per k1 block (mean 0.39, Poisson-safe)
#define SELCAP 2048
#define SSTASH 0.9915f           // stash pre-filter; expected ~800 >= 512 (10 sigma)

// ws layout:
// [0, 8K)        u32 blk_cnt[2048]
// [8K, 8K+512K)  u64 stash[2048*32]
// Overlaid on the stash region (stash is dead after k2a's gather phase;
// in-kernel barriers order gather-reads before decode-writes):
//   +8192   float4 bpk_g[512]     (8 KB)   pixel boxes
//   +16384  float  sar_g[512]     (2 KB)   areas
//   +18432  float  ssc_g[512]     (2 KB)   scores
//   +20480  u64    keepw0_g[8]    (64 B)   valid bits (pre-NMS)
//   +20544  u32    rowany_g[16]   (64 B)   row-suppresses-anything bits
//   +20608  u64    supW_g[512*8]  (32 KB)  suppression matrix

__device__ __forceinline__ uint64_t pack_key(float s, int idx) {
    // descending score, ascending index tie-break (== stable top_k)
    return ((uint64_t)__float_as_uint(s) << 32) | (uint32_t)(~idx);
}

__device__ __forceinline__ float score_of(float c0, float c1) {
    #pragma clang fp contract(off)
    float m  = fmaxf(c0, c1);
    float e0 = expf(c0 - m);
    float e1 = expf(c1 - m);
    return e1 / (e0 + e1);
}

__device__ __forceinline__ int bin_of(float s) {
    #pragma clang fp contract(off)
    int b = (int)((s - 0.9f) * 20480.0f);   // 2048 bins over (0.9, 1.0]
    return b > (NBINS - 1) ? (NBINS - 1) : b;
}

__device__ __forceinline__ uint64_t shfl_xor64(uint64_t x, int mask) {
    int lo = __shfl_xor((int)(uint32_t)x, mask, 64);
    int hi = __shfl_xor((int)(uint32_t)(x >> 32), mask, 64);
    return ((uint64_t)(uint32_t)hi << 32) | (uint32_t)lo;
}

// K1: stream conf once (full grid); stash s > SSTASH into per-block regions.
// Zero global atomics; LDS counter only.  (UNCHANGED.)
__global__ void k1_stash(const float4* __restrict__ conf4,
                         uint32_t* __restrict__ blk_cnt,
                         uint64_t* __restrict__ stash) {
    #pragma clang fp contract(off)
    __shared__ uint32_t lcnt;
    int t = threadIdx.x;            // 256 threads
    int blk = blockIdx.x;           // 2048 blocks, 512 float4 (1024 elems) each
    if (t == 0) lcnt = 0;
    __syncthreads();
    uint64_t* reg = stash + (size_t)blk * SCAP;
    #pragma unroll
    for (int i = 0; i < 2; ++i) {
        int f4i = blk * 512 + t + 256 * i;
        float4 c = conf4[f4i];
        float s0 = score_of(c.x, c.y);
        float s1 = score_of(c.z, c.w);
        if (s0 > SSTASH) {
            uint32_t p = atomicAdd(&lcnt, 1u);
            if (p < SCAP) reg[p] = pack_key(s0, f4i * 2);
        }
        if (s1 > SSTASH) {
            uint32_t p = atomicAdd(&lcnt, 1u);
            if (p < SCAP) reg[p] = pack_key(s1, f4i * 2 + 1);
        }
    }
    __syncthreads();
    if (t == 0) blk_cnt[blk] = (lcnt <= SCAP) ? lcnt : 0xFFFFFFFFu;
}

// K2a: single block: gather stash -> (exact fallback if needed) -> hybrid
// register/shuffle bitonic sort -> decode top-512 -> write to ws.
// Sort: thread t owns element t in a register (P <= 1024). Phases with
// stride j<=32 are intra-wave shfl_xor compare-exchanges (no barriers);
// only j>=64 phases round-trip LDS (2 barriers each): 55 barrier-phases -> 20.
// Keys are unique (idx in low word) so order is bit-identical to any bitonic.
__launch_bounds__(1024)
__global__ void k2a_sort(const float4* __restrict__ loc,
                         const float4* __restrict__ priors,
                         const float4* __restrict__ conf4,
                         const uint32_t* __restrict__ blk_cnt,
                         const uint64_t* stash,
                         float4* bpk_g,
                         float* sar_g,
                         float* ssc_g,
                         uint64_t* keepw0_g) {
    #pragma clang fp contract(off)
    __shared__ uint64_t sel[SELCAP];        // 16 KB
    __shared__ uint32_t hist[NBINS];        // 8 KB (fallback only)
    __shared__ uint32_t nselS, fbS;
    __shared__ int bmaxS;

    int tid = threadIdx.x;          // 1024 threads
    int lane = tid & 63, wv = tid >> 6;

    if (tid == 0) { nselS = 0u; fbS = 0u; bmaxS = 0; }
    __syncthreads();

    // ---- gather stash entries (breadth-first, ~800 expected) ----
    for (int b = tid; b < K1BLK; b += 1024) {
        uint32_t c = blk_cnt[b];
        if (c == 0xFFFFFFFFu) { atomicOr(&fbS, 1u); c = 0; }
        const uint64_t* regp = stash + (size_t)b * SCAP;
        for (uint32_t j = 0; j < c; ++j) {
            uint64_t k = regp[j];
            uint32_t p = atomicAdd(&nselS, 1u);
            if (p < SELCAP) sel[p] = k; else atomicOr(&fbS, 1u);
        }
    }
    __syncthreads();
    uint32_t n = nselS;
    bool fb = (fbS != 0u) || (n < KTOP) || (n > SELCAP);
    __syncthreads();

    if (fb) {
        // ---- exact fallback: 2-pass histogram select over all of conf ----
        if (tid == 0) nselS = 0u;
        for (int b = tid; b < NBINS; b += 1024) hist[b] = 0u;
        __syncthreads();
        for (int f = tid; f < N_PRIORS / 2; f += 1024) {
            float4 c = conf4[f];
            float s0 = score_of(c.x, c.y);
            float s1 = score_of(c.z, c.w);
            if (s0 > 0.9f) atomicAdd(&hist[bin_of(s0)], 1u);
            if (s1 > 0.9f) atomicAdd(&hist[bin_of(s1)], 1u);
        }
        __syncthreads();
        for (int off = 1; off < NBINS; off <<= 1) {
            int b0 = tid, b1 = tid + 1024;
            uint32_t v0 = hist[b0] + ((b0 + off < NBINS) ? hist[b0 + off] : 0u);
            uint32_t v1 = hist[b1] + ((b1 + off < NBINS) ? hist[b1 + off] : 0u);
            __syncthreads();
            hist[b0] = v0; hist[b1] = v1;
            __syncthreads();
        }
        if (hist[tid] >= KTOP) atomicMax(&bmaxS, tid);
        if (hist[tid + 1024] >= KTOP) atomicMax(&bmaxS, tid + 1024);
        __syncthreads();
        int B = bmaxS;
        for (int f = tid; f < N_PRIORS / 2; f += 1024) {
            float4 c = conf4[f];
            float s0 = score_of(c.x, c.y);
            float s1 = score_of(c.z, c.w);
            if (s0 > 0.9f && bin_of(s0) >= B) {
                uint32_t p = atomicAdd(&nselS, 1u);
                if (p < SELCAP) sel[p] = pack_key(s0, 2 * f);
            }
            if (s1 > 0.9f && bin_of(s1) >= B) {
                uint32_t p = atomicAdd(&nselS, 1u);
                if (p < SELCAP) sel[p] = pack_key(s1, 2 * f + 1);
            }
        }
        __syncthreads();
        n = nselS; if (n > SELCAP) n = SELCAP;
        __syncthreads();
    }

    int P = KTOP; while (P < (int)n) P <<= 1;
    for (int t = tid; t < P; t += 1024) if (t >= (int)n) sel[t] = 0ull;
    __syncthreads();

    uint64_t v;   // thread tid's element (valid for tid < min(P,1024))

    if (P <= 1024) {
        // ---- hybrid bitonic sort, descending (0-padding sinks) ----
        v = (tid < P) ? sel[tid] : 0ull;
        for (int k = 2; k <= P; k <<= 1) {
            // cross-wave phases (stride >= 64): via LDS, 2 barriers each
            for (int j = k >> 1; j >= 64; j >>= 1) {
                if (tid < P) sel[tid] = v;
                __syncthreads();
                if (tid < P) {
                    uint64_t pv = sel[tid ^ j];
                    bool wmax = (((tid & j) == 0) == ((tid & k) == 0));
                    v = wmax ? (v > pv ? v : pv) : (v < pv ? v : pv);
                }
                __syncthreads();
            }
            // intra-wave phases (stride <= 32): register shuffles, no barriers
            int j0 = (k >> 1) < 32 ? (k >> 1) : 32;
            for (int j = j0; j >= 1; j >>= 1) {
                uint64_t pv = shfl_xor64(v, j);
                bool wmax = (((tid & j) == 0) == ((tid & k) == 0));
                v = wmax ? (v > pv ? v : pv) : (v < pv ? v : pv);
            }
        }
    } else {
        // ---- rare overflow path (n > 1024): original LDS bitonic ----
        for (int k = 2; k <= P; k <<= 1) {
            for (int j = k >> 1; j > 0; j >>= 1) {
                for (int t = tid; t < P; t += 1024) {
                    int ixj = t ^ j;
                    if (ixj > t) {
                        uint64_t a = sel[t], b = sel[ixj];
                        bool sw = ((t & k) == 0) ? (a < b) : (a > b);
                        if (sw) { sel[t] = b; sel[ixj] = a; }
                    }
                }
                __syncthreads();
            }
        }
        v = (tid < KTOP) ? sel[tid] : 0ull;
    }

    // ---- decode top-512 (exact numpy op order); valid bits via ballot ----
    {
        uint64_t key = (tid < KTOP) ? v : 0ull;
        if (tid < KTOP) {
            float4 bb; float area, sc;
            if (key != 0ull) {
                sc = __uint_as_float((uint32_t)(key >> 32));
                int idx  = (int)(~(uint32_t)key);
                float4 l = loc[idx];
                float4 p = priors[idx];
                float cx = p.x + (l.x * 0.1f) * p.z;
                float cy = p.y + (l.y * 0.1f) * p.w;
                float w  = p.z * expf(l.z * 0.2f);
                float h  = p.w * expf(l.w * 0.2f);
                float x1 = cx - w * 0.5f;
                float y1 = cy - h * 0.5f;
                float x2 = x1 + w;
                float y2 = y1 + h;
                x1 *= 2048.0f; y1 *= 2048.0f; x2 *= 2048.0f; y2 *= 2048.0f;
                bb = make_float4(x1, y1, x2, y2);
                area = (x2 - x1 + 1.0f) * (y2 - y1 + 1.0f);
            } else {
                bb = make_float4(0.f, 0.f, 0.f, 0.f); area = 1.f; sc = 0.f;
            }
            bpk_g[tid] = bb; sar_g[tid] = area; ssc_g[tid] = sc;
        }
        uint64_t vb = __ballot(key != 0ull);    // wave w covers cols 64w..64w+63
        if (lane == 0 && wv < 8) keepw0_g[wv] = vb;
    }
}

// K2b: suppression matrix on 16 blocks (16 CUs). Block b owns rows
// [b*32, b*32+32); 4 waves x 8 rows. Lane L owns cols {64c+L}. Row bitmasks
// assembled by ballot: supW_g[r*8+c] bit L = (col 64c+L suppressed by row r).
// Identical FP ops as baseline -> bit-identical suppression decisions.
__launch_bounds__(256)
__global__ void k2b_supp(const float4* bpk_g, const float* sar_g,
                         uint64_t* supW_g, uint32_t* rowany_g) {
    #pragma clang fp contract(off)
    __shared__ float4 bpk[KTOP];            // 8 KB
    __shared__ float  sar[KTOP];            // 2 KB
    __shared__ uint32_t anyS;
    int tid = threadIdx.x;                  // 256 threads
    int lane = tid & 63, wv = tid >> 6;     // 4 waves
    if (tid == 0) anyS = 0u;
    for (int i = tid; i < KTOP; i += 256) { bpk[i] = bpk_g[i]; sar[i] = sar_g[i]; }
    __syncthreads();

    float4 cb0 = bpk[lane +   0], cb1 = bpk[lane +  64];
    float4 cb2 = bpk[lane + 128], cb3 = bpk[lane + 192];
    float4 cb4 = bpk[lane + 256], cb5 = bpk[lane + 320];
    float4 cb6 = bpk[lane + 384], cb7 = bpk[lane + 448];
    // identical formula+inputs as decode -> bit-identical areas
    float ca0 = (cb0.z - cb0.x + 1.0f) * (cb0.w - cb0.y + 1.0f);
    float ca1 = (cb1.z - cb1.x + 1.0f) * (cb1.w - cb1.y + 1.0f);
    float ca2 = (cb2.z - cb2.x + 1.0f) * (cb2.w - cb2.y + 1.0f);
    float ca3 = (cb3.z - cb3.x + 1.0f) * (cb3.w - cb3.y + 1.0f);
    float ca4 = (cb4.z - cb4.x + 1.0f) * (cb4.w - cb4.y + 1.0f);
    float ca5 = (cb5.z - cb5.x + 1.0f) * (cb5.w - cb5.y + 1.0f);
    float ca6 = (cb6.z - cb6.x + 1.0f) * (cb6.w - cb6.y + 1.0f);
    float ca7 = (cb7.z - cb7.x + 1.0f) * (cb7.w - cb7.y + 1.0f);

    #define SUPC(c, CB, CA) do { \
        float xx1 = fmaxf(rb.x, CB.x); float yy1 = fmaxf(rb.y, CB.y); \
        float xx2 = fminf(rb.z, CB.z); float yy2 = fminf(rb.w, CB.w); \
        float ww = fmaxf(xx2 - xx1 + 1.0f, 0.0f); \
        float hh = fmaxf(yy2 - yy1 + 1.0f, 0.0f); \
        float inter = ww * hh; \
        float iou = inter / (ra + (CA) - inter); \
        uint64_t wrd = __ballot(iou > 0.4f && (64 * (c) + lane) > r); \
        if (lane == 0) supW_g[r * 8 + (c)] = wrd; \
        any |= wrd; } while (0)

    uint32_t mybits = 0u;
    int rbase = blockIdx.x * 32 + wv * 8;
    for (int rr = 0; rr < 8; ++rr) {
        int r = rbase + rr;
        float4 rb = bpk[r];     // wave-uniform broadcast
        float ra = sar[r];
        uint64_t any = 0ull;
        SUPC(0, cb0, ca0); SUPC(1, cb1, ca1); SUPC(2, cb2, ca2); SUPC(3, cb3, ca3);
        SUPC(4, cb4, ca4); SUPC(5, cb5, ca5); SUPC(6, cb6, ca6); SUPC(7, cb7, ca7);
        if (lane == 0 && any != 0ull) mybits |= 1u << (r & 31);
    }
    #undef SUPC
    if (lane == 0 && mybits != 0u) atomicOr(&anyS, mybits);
    __syncthreads();
    if (tid == 0) rowany_g[blockIdx.x] = anyS;   // rows b*32.. -> word b exactly
}

// K2c: greedy bitmask scan (1 thread; rare rows) + epilogue.
__launch_bounds__(512)
__global__ void k2c_final(const float4* bpk_g, const float* ssc_g,
                          const uint64_t* keepw0_g, const uint32_t* rowany_g,
                          const uint64_t* supW_g, float* __restrict__ out) {
    #pragma clang fp contract(off)
    __shared__ uint64_t supW[KTOP * 8];     // 32 KB
    __shared__ uint64_t keepw[8];
    int tid = threadIdx.x;                  // 512 threads
    for (int i = tid; i < KTOP * 8; i += 512) supW[i] = supW_g[i];
    __syncthreads();

    if (tid == 0) {
        #define RA64(c) (((uint64_t)rowany_g[2*(c)]) | (((uint64_t)rowany_g[2*(c)+1]) << 32))
        uint64_t kp0 = keepw0_g[0], kp1 = keepw0_g[1], kp2 = keepw0_g[2], kp3 = keepw0_g[3];
        uint64_t kp4 = keepw0_g[4], kp5 = keepw0_g[5], kp6 = keepw0_g[6], kp7 = keepw0_g[7];
        #define APPLYROW(i) do { const uint64_t* rp = supW + (size_t)(i) * 8; \
            kp0 &= ~rp[0]; kp1 &= ~rp[1]; kp2 &= ~rp[2]; kp3 &= ~rp[3]; \
            kp4 &= ~rp[4]; kp5 &= ~rp[5]; kp6 &= ~rp[6]; kp7 &= ~rp[7]; } while (0)
        #define CHUNK(c, KPC) do { uint64_t ra = RA64(c); uint64_t m = (KPC) & ra; \
            while (m) { int b = __builtin_ctzll(m); APPLYROW((c) * 64 + b); \
                uint64_t above = (b == 63) ? 0ull : (~0ull << (b + 1)); \
                m = (KPC) & ra & above; } } while (0)
        CHUNK(0, kp0); CHUNK(1, kp1); CHUNK(2, kp2); CHUNK(3, kp3);
        CHUNK(4, kp4); CHUNK(5, kp5); CHUNK(6, kp6); CHUNK(7, kp7);
        keepw[0] = kp0; keepw[1] = kp1; keepw[2] = kp2; keepw[3] = kp3;
        keepw[4] = kp4; keepw[5] = kp5; keepw[6] = kp6; keepw[7] = kp7;
        #undef CHUNK
        #undef APPLYROW
        #undef RA64
    }
    __syncthreads();

    // ---- epilogue: [512,5], boxes /2048 (exact pow2), zeros if suppressed ----
    if (tid < KTOP) {
        const float inv = 1.0f / 2048.0f;
        int kb = (int)((keepw[tid >> 6] >> (tid & 63)) & 1ull);
        float4 bb = bpk_g[tid];
        float sc = ssc_g[tid];
        float* o = out + tid * 5;
        if (kb) {
            o[0] = bb.x * inv;
            o[1] = bb.y * inv;
            o[2] = bb.z * inv;
            o[3] = bb.w * inv;
            o[4] = sc;
        } else {
            o[0] = 0.f; o[1] = 0.f; o[2] = 0.f; o[3] = 0.f; o[4] = 0.f;
        }
    }
}

extern "C" void kernel_launch(void* const* d_in, const int* in_sizes, int n_in,
                              void* d_out, int out_size, void* d_ws, size_t ws_size,
                              hipStream_t stream) {
    const float* loc    = (const float*)d_in[0];   // [1,N,4]
    const float* conf   = (const float*)d_in[1];   // [1,N,2]
    const float* priors = (const float*)d_in[2];   // [N,4]
    float* out = (float*)d_out;                    // [512,5]

    uint8_t* ws = (uint8_t*)d_ws;
    uint32_t* blk_cnt = (uint32_t*)ws;             // 8 KB
    uint64_t* stash   = (uint64_t*)(ws + 8192);    // 512 KB
    // overlays on stash (dead after k2a gather):
    float4*   bpk_g    = (float4*)(ws + 8192);     // 8 KB
    float*    sar_g    = (float*)(ws + 16384);     // 2 KB
    float*    ssc_g    = (float*)(ws + 18432);     // 2 KB
    uint64_t* keepw0_g = (uint64_t*)(ws + 20480);  // 64 B
    uint32_t* rowany_g = (uint32_t*)(ws + 20544);  // 64 B
    uint64_t* supW_g   = (uint64_t*)(ws + 20608);  // 32 KB

    // no memset needed: blk_cnt fully written by K1; all overlay arrays are
    // fully written by their producer kernel before any consumer reads them.
    k1_stash<<<K1BLK, 256, 0, stream>>>((const float4*)conf, blk_cnt, stash);
    k2a_sort<<<1, 1024, 0, stream>>>((const float4*)loc, (const float4*)priors,
                                     (const float4*)conf, blk_cnt, stash,
                                     bpk_g, sar_g, ssc_g, keepw0_g);
    k2b_supp<<<16, 256, 0, stream>>>(bpk_g, sar_g, supW_g, rowany_g);
    k2c_final<<<1, 512, 0, stream>>>(bpk_g, ssc_g, keepw0_g, rowany_g, supW_g, out);
}

// Round 3
// 134.115 us; speedup vs baseline: 1.3326x; 1.0124x over previous
//
#include <hip/hip_runtime.h>
#include <stdint.h>

// Problem constants (match reference)
#define N_PRIORS 2097152
#define KTOP 512
#define NBINS 2048
#define K1BLK 2048
#define SCAP 32                  // stash slots per k1 block (mean 0.39, Poisson-safe)
#define SELCAP 2048
#define SSTASH 0.9915f           // stash pre-filter; expected ~800 >= 512 (10 sigma)
#define NSUPB 16                 // suppression blocks (each owns 32 rows)

// ws layout:
// [0, 8K)           u32 blk_cnt[2048]
// [8K, 8K+512K)     u64 stash[2048*32]
// +532480           u32 done counter (init by k1)
// +532544           u32 rowany_g[16]
// +532608           u64 supW_g[512*8]  (32 KB)
//
// Everything else (boxes/areas/scores/keep-bits) lives in LDS only: all 16
// blocks of k2_fused redundantly compute gather+sort+decode (bit-identical:
// keys are unique, so the sorted order is independent of gather atomics).

__device__ __forceinline__ uint64_t pack_key(float s, int idx) {
    // descending score, ascending index tie-break (== stable top_k)
    return ((uint64_t)__float_as_uint(s) << 32) | (uint32_t)(~idx);
}

__device__ __forceinline__ float score_of(float c0, float c1) {
    #pragma clang fp contract(off)
    float m  = fmaxf(c0, c1);
    float e0 = expf(c0 - m);
    float e1 = expf(c1 - m);
    return e1 / (e0 + e1);
}

__device__ __forceinline__ int bin_of(float s) {
    #pragma clang fp contract(off)
    int b = (int)((s - 0.9f) * 20480.0f);   // 2048 bins over (0.9, 1.0]
    return b > (NBINS - 1) ? (NBINS - 1) : b;
}

__device__ __forceinline__ uint64_t shfl_xor64(uint64_t x, int mask) {
    int lo = __shfl_xor((int)(uint32_t)x, mask, 64);
    int hi = __shfl_xor((int)(uint32_t)(x >> 32), mask, 64);
    return ((uint64_t)(uint32_t)hi << 32) | (uint32_t)lo;
}

// K1: stream conf once (full grid); stash s > SSTASH into per-block regions.
// Zero global atomics; LDS counter only. Also inits the k2 tail counter.
__global__ void k1_stash(const float4* __restrict__ conf4,
                         uint32_t* __restrict__ blk_cnt,
                         uint64_t* __restrict__ stash,
                         uint32_t* __restrict__ done_g) {
    #pragma clang fp contract(off)
    __shared__ uint32_t lcnt;
    int t = threadIdx.x;            // 256 threads
    int blk = blockIdx.x;           // 2048 blocks, 512 float4 (1024 elems) each
    if (blk == 0 && t == 0) *done_g = 0u;    // reset tail counter for k2
    if (t == 0) lcnt = 0;
    __syncthreads();
    uint64_t* reg = stash + (size_t)blk * SCAP;
    #pragma unroll
    for (int i = 0; i < 2; ++i) {
        int f4i = blk * 512 + t + 256 * i;
        float4 c = conf4[f4i];
        float s0 = score_of(c.x, c.y);
        float s1 = score_of(c.z, c.w);
        if (s0 > SSTASH) {
            uint32_t p = atomicAdd(&lcnt, 1u);
            if (p < SCAP) reg[p] = pack_key(s0, f4i * 2);
        }
        if (s1 > SSTASH) {
            uint32_t p = atomicAdd(&lcnt, 1u);
            if (p < SCAP) reg[p] = pack_key(s1, f4i * 2 + 1);
        }
    }
    __syncthreads();
    if (t == 0) blk_cnt[blk] = (lcnt <= SCAP) ? lcnt : 0xFFFFFFFFu;
}

// K2 (fused): 16 blocks x 1024 threads.
// Phase 1 (all blocks, redundant, bit-identical): gather stash -> (exact
//   fallback if needed) -> hybrid register/shuffle bitonic sort -> decode
//   top-512 into LDS (bpk/sar/ssc/keepw0).
// Phase 2: block b computes suppression-matrix rows [b*32, b*32+32)
//   (16 waves x 2 rows) from its LDS boxes; writes supW_g + rowany_g[b].
// Phase 3: last-arriving block (device atomicAdd on done_g) stages supW_g
//   via agent-scope atomic loads, runs the greedy bitmask scan + epilogue.
__launch_bounds__(1024)
__global__ void k2_fused(const float4* __restrict__ loc,
                         const float4* __restrict__ priors,
                         const float4* __restrict__ conf4,
                         const uint32_t* __restrict__ blk_cnt,
                         const uint64_t* __restrict__ stash,
                         uint32_t* done_g,
                         uint32_t* rowany_g,
                         uint64_t* supW_g,
                         float* __restrict__ out) {
    #pragma clang fp contract(off)
    __shared__ uint64_t arena[4096];        // 32 KB: sel[0..2048) then supW stage
    uint64_t* sel  = arena;
    uint64_t* supW = arena;                 // tail phase only (sel dead)
    __shared__ uint32_t hist[NBINS];        // 8 KB (fallback only)
    __shared__ float4 bpk[KTOP];            // 8 KB pixel boxes
    __shared__ float  sar[KTOP], ssc[KTOP]; // 4 KB
    __shared__ uint64_t keepw0[8];          // valid bits (pre-NMS)
    __shared__ uint64_t keepw[8];           // final keep bits
    __shared__ uint32_t rowanyL[16];
    __shared__ uint32_t nselS, fbS, anyS, tailS;
    __shared__ int bmaxS;

    int tid = threadIdx.x;          // 1024 threads
    int lane = tid & 63, wv = tid >> 6;

    if (tid == 0) { nselS = 0u; fbS = 0u; bmaxS = 0; anyS = 0u; }
    __syncthreads();

    // ---- gather stash entries (breadth-first, ~800 expected) ----
    for (int b = tid; b < K1BLK; b += 1024) {
        uint32_t c = blk_cnt[b];
        if (c == 0xFFFFFFFFu) { atomicOr(&fbS, 1u); c = 0; }
        const uint64_t* regp = stash + (size_t)b * SCAP;
        for (uint32_t j = 0; j < c; ++j) {
            uint64_t k = regp[j];
            uint32_t p = atomicAdd(&nselS, 1u);
            if (p < SELCAP) sel[p] = k; else atomicOr(&fbS, 1u);
        }
    }
    __syncthreads();
    uint32_t n = nselS;
    bool fb = (fbS != 0u) || (n < KTOP) || (n > SELCAP);
    __syncthreads();

    if (fb) {
        // ---- exact fallback: 2-pass histogram select over all of conf ----
        if (tid == 0) nselS = 0u;
        for (int b = tid; b < NBINS; b += 1024) hist[b] = 0u;
        __syncthreads();
        for (int f = tid; f < N_PRIORS / 2; f += 1024) {
            float4 c = conf4[f];
            float s0 = score_of(c.x, c.y);
            float s1 = score_of(c.z, c.w);
            if (s0 > 0.9f) atomicAdd(&hist[bin_of(s0)], 1u);
            if (s1 > 0.9f) atomicAdd(&hist[bin_of(s1)], 1u);
        }
        __syncthreads();
        for (int off = 1; off < NBINS; off <<= 1) {
            int b0 = tid, b1 = tid + 1024;
            uint32_t v0 = hist[b0] + ((b0 + off < NBINS) ? hist[b0 + off] : 0u);
            uint32_t v1 = hist[b1] + ((b1 + off < NBINS) ? hist[b1 + off] : 0u);
            __syncthreads();
            hist[b0] = v0; hist[b1] = v1;
            __syncthreads();
        }
        if (hist[tid] >= KTOP) atomicMax(&bmaxS, tid);
        if (hist[tid + 1024] >= KTOP) atomicMax(&bmaxS, tid + 1024);
        __syncthreads();
        int B = bmaxS;
        for (int f = tid; f < N_PRIORS / 2; f += 1024) {
            float4 c = conf4[f];
            float s0 = score_of(c.x, c.y);
            float s1 = score_of(c.z, c.w);
            if (s0 > 0.9f && bin_of(s0) >= B) {
                uint32_t p = atomicAdd(&nselS, 1u);
                if (p < SELCAP) sel[p] = pack_key(s0, 2 * f);
            }
            if (s1 > 0.9f && bin_of(s1) >= B) {
                uint32_t p = atomicAdd(&nselS, 1u);
                if (p < SELCAP) sel[p] = pack_key(s1, 2 * f + 1);
            }
        }
        __syncthreads();
        n = nselS; if (n > SELCAP) n = SELCAP;
        __syncthreads();
    }

    int P = KTOP; while (P < (int)n) P <<= 1;
    for (int t = tid; t < P; t += 1024) if (t >= (int)n) sel[t] = 0ull;
    __syncthreads();

    uint64_t v;   // thread tid's element (valid for tid < min(P,1024))

    if (P <= 1024) {
        // ---- hybrid bitonic sort, descending (0-padding sinks) ----
        v = (tid < P) ? sel[tid] : 0ull;
        for (int k = 2; k <= P; k <<= 1) {
            // cross-wave phases (stride >= 64): via LDS, 2 barriers each
            for (int j = k >> 1; j >= 64; j >>= 1) {
                if (tid < P) sel[tid] = v;
                __syncthreads();
                if (tid < P) {
                    uint64_t pv = sel[tid ^ j];
                    bool wmax = (((tid & j) == 0) == ((tid & k) == 0));
                    v = wmax ? (v > pv ? v : pv) : (v < pv ? v : pv);
                }
                __syncthreads();
            }
            // intra-wave phases (stride <= 32): register shuffles, no barriers
            int j0 = (k >> 1) < 32 ? (k >> 1) : 32;
            for (int j = j0; j >= 1; j >>= 1) {
                uint64_t pv = shfl_xor64(v, j);
                bool wmax = (((tid & j) == 0) == ((tid & k) == 0));
                v = wmax ? (v > pv ? v : pv) : (v < pv ? v : pv);
            }
        }
    } else {
        // ---- rare overflow path (n > 1024): original LDS bitonic ----
        for (int k = 2; k <= P; k <<= 1) {
            for (int j = k >> 1; j > 0; j >>= 1) {
                for (int t = tid; t < P; t += 1024) {
                    int ixj = t ^ j;
                    if (ixj > t) {
                        uint64_t a = sel[t], b = sel[ixj];
                        bool sw = ((t & k) == 0) ? (a < b) : (a > b);
                        if (sw) { sel[t] = b; sel[ixj] = a; }
                    }
                }
                __syncthreads();
            }
        }
        v = (tid < KTOP) ? sel[tid] : 0ull;
    }

    // ---- decode top-512 (exact numpy op order) into LDS; valid-bit ballot ----
    {
        uint64_t key = (tid < KTOP) ? v : 0ull;
        if (tid < KTOP) {
            float4 bb; float area, sc;
            if (key != 0ull) {
                sc = __uint_as_float((uint32_t)(key >> 32));
                int idx  = (int)(~(uint32_t)key);
                float4 l = loc[idx];
                float4 p = priors[idx];
                float cx = p.x + (l.x * 0.1f) * p.z;
                float cy = p.y + (l.y * 0.1f) * p.w;
                float w  = p.z * expf(l.z * 0.2f);
                float h  = p.w * expf(l.w * 0.2f);
                float x1 = cx - w * 0.5f;
                float y1 = cy - h * 0.5f;
                float x2 = x1 + w;
                float y2 = y1 + h;
                x1 *= 2048.0f; y1 *= 2048.0f; x2 *= 2048.0f; y2 *= 2048.0f;
                bb = make_float4(x1, y1, x2, y2);
                area = (x2 - x1 + 1.0f) * (y2 - y1 + 1.0f);
            } else {
                bb = make_float4(0.f, 0.f, 0.f, 0.f); area = 1.f; sc = 0.f;
            }
            bpk[tid] = bb; sar[tid] = area; ssc[tid] = sc;
        }
        uint64_t vb = __ballot(key != 0ull);    // wave w covers cols 64w..64w+63
        if (lane == 0 && wv < 8) keepw0[wv] = vb;
    }
    __syncthreads();    // bpk/sar/ssc/keepw0 ready; sel dead

    // ---- suppression rows for this block: 16 waves x 2 rows ----
    {
        float4 cb0 = bpk[lane +   0], cb1 = bpk[lane +  64];
        float4 cb2 = bpk[lane + 128], cb3 = bpk[lane + 192];
        float4 cb4 = bpk[lane + 256], cb5 = bpk[lane + 320];
        float4 cb6 = bpk[lane + 384], cb7 = bpk[lane + 448];
        // identical formula+inputs as decode -> bit-identical areas
        float ca0 = (cb0.z - cb0.x + 1.0f) * (cb0.w - cb0.y + 1.0f);
        float ca1 = (cb1.z - cb1.x + 1.0f) * (cb1.w - cb1.y + 1.0f);
        float ca2 = (cb2.z - cb2.x + 1.0f) * (cb2.w - cb2.y + 1.0f);
        float ca3 = (cb3.z - cb3.x + 1.0f) * (cb3.w - cb3.y + 1.0f);
        float ca4 = (cb4.z - cb4.x + 1.0f) * (cb4.w - cb4.y + 1.0f);
        float ca5 = (cb5.z - cb5.x + 1.0f) * (cb5.w - cb5.y + 1.0f);
        float ca6 = (cb6.z - cb6.x + 1.0f) * (cb6.w - cb6.y + 1.0f);
        float ca7 = (cb7.z - cb7.x + 1.0f) * (cb7.w - cb7.y + 1.0f);
        #define SUPC(c, CB, CA) do { \
            float xx1 = fmaxf(rb.x, CB.x); float yy1 = fmaxf(rb.y, CB.y); \
            float xx2 = fminf(rb.z, CB.z); float yy2 = fminf(rb.w, CB.w); \
            float ww = fmaxf(xx2 - xx1 + 1.0f, 0.0f); \
            float hh = fmaxf(yy2 - yy1 + 1.0f, 0.0f); \
            float inter = ww * hh; \
            float iou = inter / (ra + (CA) - inter); \
            uint64_t wrd = __ballot(iou > 0.4f && (64 * (c) + lane) > r); \
            if (lane == 0) supW_g[r * 8 + (c)] = wrd; \
            any |= wrd; } while (0)
        uint32_t mybits = 0u;
        int rbase = blockIdx.x * 32 + wv * 2;
        for (int rr = 0; rr < 2; ++rr) {
            int r = rbase + rr;
            float4 rb = bpk[r];     // wave-uniform broadcast
            float ra = sar[r];
            uint64_t any = 0ull;
            SUPC(0, cb0, ca0); SUPC(1, cb1, ca1); SUPC(2, cb2, ca2); SUPC(3, cb3, ca3);
            SUPC(4, cb4, ca4); SUPC(5, cb5, ca5); SUPC(6, cb6, ca6); SUPC(7, cb7, ca7);
            if (lane == 0 && any != 0ull) mybits |= 1u << (r & 31);
        }
        #undef SUPC
        if (lane == 0 && mybits != 0u) atomicOr(&anyS, mybits);
    }
    __syncthreads();    // all supW_g stores of this block drained (barrier waits vmcnt)

    // ---- arrival: release fence + device counter; last block is the tail ----
    if (tid == 0) {
        rowany_g[blockIdx.x] = anyS;    // rows b*32.. -> word b exactly
        __threadfence();                // order my block's global writes
        uint32_t old = atomicAdd(done_g, 1u);
        tailS = (old == (uint32_t)(NSUPB - 1)) ? 1u : 0u;
    }
    __syncthreads();
    if (tailS == 0u) return;

    // ---- tail block: stage supW/rowany coherently, greedy scan, epilogue ----
    __threadfence();    // acquire side
    for (int i = tid; i < KTOP * 8; i += 1024)
        supW[i] = __hip_atomic_load(&supW_g[i], __ATOMIC_RELAXED,
                                    __HIP_MEMORY_SCOPE_AGENT);
    if (tid < 16)
        rowanyL[tid] = __hip_atomic_load(&rowany_g[tid], __ATOMIC_RELAXED,
                                         __HIP_MEMORY_SCOPE_AGENT);
    __syncthreads();

    if (tid == 0) {
        #define RA64(c) (((uint64_t)rowanyL[2*(c)]) | (((uint64_t)rowanyL[2*(c)+1]) << 32))
        uint64_t kp0 = keepw0[0], kp1 = keepw0[1], kp2 = keepw0[2], kp3 = keepw0[3];
        uint64_t kp4 = keepw0[4], kp5 = keepw0[5], kp6 = keepw0[6], kp7 = keepw0[7];
        #define APPLYROW(i) do { const uint64_t* rp = supW + (size_t)(i) * 8; \
            kp0 &= ~rp[0]; kp1 &= ~rp[1]; kp2 &= ~rp[2]; kp3 &= ~rp[3]; \
            kp4 &= ~rp[4]; kp5 &= ~rp[5]; kp6 &= ~rp[6]; kp7 &= ~rp[7]; } while (0)
        #define CHUNK(c, KPC) do { uint64_t ra = RA64(c); uint64_t m = (KPC) & ra; \
            while (m) { int b = __builtin_ctzll(m); APPLYROW((c) * 64 + b); \
                uint64_t above = (b == 63) ? 0ull : (~0ull << (b + 1)); \
                m = (KPC) & ra & above; } } while (0)
        CHUNK(0, kp0); CHUNK(1, kp1); CHUNK(2, kp2); CHUNK(3, kp3);
        CHUNK(4, kp4); CHUNK(5, kp5); CHUNK(6, kp6); CHUNK(7, kp7);
        keepw[0] = kp0; keepw[1] = kp1; keepw[2] = kp2; keepw[3] = kp3;
        keepw[4] = kp4; keepw[5] = kp5; keepw[6] = kp6; keepw[7] = kp7;
        #undef CHUNK
        #undef APPLYROW
        #undef RA64
    }
    __syncthreads();

    // ---- epilogue: [512,5], boxes /2048 (exact pow2), zeros if suppressed ----
    if (tid < KTOP) {
        const float inv = 1.0f / 2048.0f;
        int kb = (int)((keepw[tid >> 6] >> (tid & 63)) & 1ull);
        float4 bb = bpk[tid];
        float* o = out + tid * 5;
        if (kb) {
            o[0] = bb.x * inv;
            o[1] = bb.y * inv;
            o[2] = bb.z * inv;
            o[3] = bb.w * inv;
            o[4] = ssc[tid];
        } else {
            o[0] = 0.f; o[1] = 0.f; o[2] = 0.f; o[3] = 0.f; o[4] = 0.f;
        }
    }
}

extern "C" void kernel_launch(void* const* d_in, const int* in_sizes, int n_in,
                              void* d_out, int out_size, void* d_ws, size_t ws_size,
                              hipStream_t stream) {
    const float* loc    = (const float*)d_in[0];   // [1,N,4]
    const float* conf   = (const float*)d_in[1];   // [1,N,2]
    const float* priors = (const float*)d_in[2];   // [N,4]
    float* out = (float*)d_out;                    // [512,5]

    uint8_t* ws = (uint8_t*)d_ws;
    uint32_t* blk_cnt  = (uint32_t*)ws;              // 8 KB
    uint64_t* stash    = (uint64_t*)(ws + 8192);     // 512 KB (ends 532480)
    uint32_t* done_g   = (uint32_t*)(ws + 532480);   // 4 B (reset by k1)
    uint32_t* rowany_g = (uint32_t*)(ws + 532544);   // 64 B
    uint64_t* supW_g   = (uint64_t*)(ws + 532608);   // 32 KB

    // no memset needed: blk_cnt + done_g fully written by k1 before k2 reads;
    // supW_g/rowany_g fully written by k2 blocks before the tail reads them
    // (threadfence + device-scope atomic arrival, agent-scope staged loads).
    k1_stash<<<K1BLK, 256, 0, stream>>>((const float4*)conf, blk_cnt, stash, done_g);
    k2_fused<<<NSUPB, 1024, 0, stream>>>((const float4*)loc, (const float4*)priors,
                                         (const float4*)conf, blk_cnt, stash,
                                         done_g, rowany_g, supW_g, out);
}